// Round 9
// baseline (370.024 us; speedup 1.0000x reference)
//
#include <hip/hip_runtime.h>
#include <hip/hip_bf16.h>
#include <cstdint>
#include <cstddef>

#define N_NODES 50000
#define DEG     24
#define NEDGE   (N_NODES*DEG)
#define RSZ     500
#define NDIM    64
#define FEATD   192

// LDS row stride (shorts) for the 16x200 per-wave transpose buffer in k_gate.
#define LSTR    200

// Fused layer kernel: 784 blocks x 256 thr, VGPR<=128 (launch_bounds(256,4))
// -> 4 blocks/CU capacity = 1024 >= 784, all blocks co-resident (no deadlock).
// Each block does logical groups {b, b+784} per layer; XCD swizzle preserved
// ((b+784)&7 == b&7, so both groups land in the same XCD node chunk).
#define NBLK    784
#define LCHUNK  196

typedef short bf16x8 __attribute__((ext_vector_type(8)));
typedef float f32x4  __attribute__((ext_vector_type(4)));

__device__ __forceinline__ unsigned short f2bf(float f) {
    unsigned u = __builtin_bit_cast(unsigned, f);
    unsigned r = (u + 0x7fffu + ((u >> 16) & 1u)) >> 16;   // RNE
    return (unsigned short)r;
}
__device__ __forceinline__ float bf2f(unsigned short s) {
    unsigned u = ((unsigned)s) << 16;
    return __builtin_bit_cast(float, u);
}
__device__ __forceinline__ float lo16(unsigned u) {
    return __builtin_bit_cast(float, u << 16);
}
__device__ __forceinline__ float hi16(unsigned u) {
    return __builtin_bit_cast(float, u & 0xFFFF0000u);
}
__device__ __forceinline__ float fast_tanh(float x) {
    float e = __expf(2.f * x);
    return 1.f - 2.f / (e + 1.f);
}

// ---- PREP (fused) — R4-exact form + barrier-counter zeroing -----------------
// Block ranges: [0,3125) tanh, [3125,3250) rel, [3250,3266) pninv,
//               [3266,3506) packB, [3506,4678) packE.
__global__ __launch_bounds__(256) void k_prep(const float* __restrict__ features,
                                              const float* __restrict__ rel_emb,
                                              const float* __restrict__ attn_k,
                                              const float* __restrict__ proxy,
                                              const float* __restrict__ gate_w,
                                              const int* __restrict__ src,
                                              const int* __restrict__ rel,
                                              unsigned short* __restrict__ fin0,
                                              float* __restrict__ reln,
                                              float* __restrict__ expdot,
                                              float* __restrict__ pninv,
                                              unsigned short* __restrict__ B1,
                                              unsigned short* __restrict__ B2,
                                              unsigned short* __restrict__ B3,
                                              unsigned int* __restrict__ pedge,
                                              unsigned int* __restrict__ bar) {
    int b = blockIdx.x;
    if (b == 0 && threadIdx.x < 2) bar[threadIdx.x] = 0;   // re-arm grid barrier
    if (b < 3125) {
        int t = b * 256 + threadIdx.x;             // 800000 threads, 4 elems each
        int idx4 = t * 4;
        float4 f = *reinterpret_cast<const float4*>(features + idx4);
        uint2 w;
        w.x = (unsigned)f2bf(fast_tanh(f.x)) | ((unsigned)f2bf(fast_tanh(f.y)) << 16);
        w.y = (unsigned)f2bf(fast_tanh(f.z)) | ((unsigned)f2bf(fast_tanh(f.w)) << 16);
        *reinterpret_cast<uint2*>(fin0 + idx4) = w;
    } else if (b < 3250) {
        int lane = threadIdx.x & 63;
        int row = (b - 3125) * 4 + (threadIdx.x >> 6);   // 500 rows
        float v = rel_emb[row * 64 + lane];
        float ss = v * v;
        for (int m = 1; m < 64; m <<= 1) ss += __shfl_xor(ss, m);
        float inv = 1.f / fmaxf(sqrtf(ss), 1e-12f);
        float rn = v * inv;
        reln[row * 64 + lane] = rn;
        float d0 = rn * attn_k[lane];
        float d1 = rn * attn_k[64 + lane];
        for (int m = 1; m < 64; m <<= 1) { d0 += __shfl_xor(d0, m); d1 += __shfl_xor(d1, m); }
        if (lane == 0) { expdot[row] = __expf(d0); expdot[RSZ + row] = __expf(d1); }
    } else if (b < 3266) {
        int lane = threadIdx.x & 63;
        int row = (b - 3250) * 4 + (threadIdx.x >> 6);   // 64 rows
        const float* p = proxy + (size_t)row * FEATD;
        float a = p[lane], bb = p[64 + lane], c = p[128 + lane];
        float ss = a * a + bb * bb + c * c;
        for (int m = 1; m < 64; m <<= 1) ss += __shfl_xor(ss, m);
        if (lane == 0) pninv[row] = 1.f / fmaxf(sqrtf(ss), 1e-12f);
    } else if (b < 3506) {
        // B-frag for 16x16x32: lane holds B[k=(lane>>4)*8+j][n=lane&15], j=0..7
        int idx = (b - 3266) * 256 + threadIdx.x;        // 61440 threads
        int j = idx & 7, lane = (idx >> 3) & 63;
        int t = idx >> 9;
        int lane16 = lane & 15, quad = lane >> 4;
        if (t < 24) {                 // B1: Bmat[k][n] = proxy[n][k]
            int kt = t >> 2, nt = t & 3;
            int k = kt * 32 + quad * 8 + j, n = nt * 16 + lane16;
            B1[idx] = f2bf(proxy[(size_t)n * FEATD + k]);
        } else if (t < 48) {          // B2: pa@proxy, Bmat[k][n] = proxy[k][n]
            int tt = t - 24, kt = tt / 12, nt = tt % 12;
            int k = kt * 32 + quad * 8 + j, n = nt * 16 + lane16;
            B2[idx - 12288] = f2bf(proxy[(size_t)k * FEATD + n]);
        } else {                      // B3: pf@gate_w^T, Bmat[k][n] = gate_w[n][k]
            int tt = t - 48, kt = tt / 12, nt = tt % 12;
            int k = kt * 32 + quad * 8 + j, n = nt * 16 + lane16;
            B3[idx - 24576] = f2bf(gate_w[(size_t)n * FEATD + k]);
        }
    } else {
        // pack edges: pe = s | (r<<16)   (s < 65536, r < 512)
        int t = (b - 3506) * 256 + threadIdx.x;          // need 300000
        if (t < NEDGE / 4) {
            int4 s4 = *reinterpret_cast<const int4*>(src + t * 4);
            int4 r4 = *reinterpret_cast<const int4*>(rel + t * 4);
            uint4 o;
            o.x = (unsigned)s4.x | ((unsigned)r4.x << 16);
            o.y = (unsigned)s4.y | ((unsigned)r4.y << 16);
            o.z = (unsigned)s4.z | ((unsigned)r4.z << 16);
            o.w = (unsigned)s4.w | ((unsigned)r4.w << 16);
            *reinterpret_cast<uint4*>(pedge + t * 4) = o;
        }
    }
}

// ---- One layer pass for one logical group (R0-proven inner loop, untouched) -
__device__ __forceinline__ void layer_pass(int lg, int tid,
                                           const unsigned int* __restrict__ pedge,
                                           const float* __restrict__ reln,
                                           const float* __restrict__ expdot_l,
                                           const unsigned short* __restrict__ fin,
                                           unsigned short* __restrict__ fout) {
    int lb = (lg & 7) * LCHUNK + (lg >> 3);
    int lane8 = tid & 7;
    int node = lb * 32 + (tid >> 3);
    if (node >= N_NODES) return;                  // helper-local; barrier is outside
    int ebase = node * DEG;
    unsigned pk[DEG];
#pragma unroll
    for (int k = 0; k < DEG; k++) pk[k] = pedge[ebase + k];
    float a0 = 0.f, a1 = 0.f, a2 = 0.f, a3 = 0.f;
    float a4 = 0.f, a5 = 0.f, a6 = 0.f, a7 = 0.f, den = 0.f;
#pragma unroll 4
    for (int k = 0; k < DEG; k++) {
        unsigned p = pk[k];
        int s = p & 0xFFFF;
        int r = p >> 16;
        float ex = expdot_l[r];
        const float* tp = reln + (size_t)r * 64 + lane8 * 8;
        float4 t0 = *reinterpret_cast<const float4*>(tp);
        float4 t1v = *reinterpret_cast<const float4*>(tp + 4);
        uint4 u = *reinterpret_cast<const uint4*>(fin + (size_t)s * 64 + lane8 * 8);
        float n0 = lo16(u.x), n1 = hi16(u.x), n2 = lo16(u.y), n3 = hi16(u.y);
        float n4 = lo16(u.z), n5 = hi16(u.z), n6 = lo16(u.w), n7 = hi16(u.w);
        float pd = t0.x * n0 + t0.y * n1 + t0.z * n2 + t0.w * n3
                 + t1v.x * n4 + t1v.y * n5 + t1v.z * n6 + t1v.w * n7;
        pd += __shfl_xor(pd, 1); pd += __shfl_xor(pd, 2); pd += __shfl_xor(pd, 4);
        float t1 = -2.f * pd * ex;          // acc += ex*(nv - 2*dot*tv)
        a0 = fmaf(ex, n0, fmaf(t1, t0.x, a0));
        a1 = fmaf(ex, n1, fmaf(t1, t0.y, a1));
        a2 = fmaf(ex, n2, fmaf(t1, t0.z, a2));
        a3 = fmaf(ex, n3, fmaf(t1, t0.w, a3));
        a4 = fmaf(ex, n4, fmaf(t1, t1v.x, a4));
        a5 = fmaf(ex, n5, fmaf(t1, t1v.y, a5));
        a6 = fmaf(ex, n6, fmaf(t1, t1v.z, a6));
        a7 = fmaf(ex, n7, fmaf(t1, t1v.w, a7));
        den += ex;
    }
    float id = 1.f / den;
    uint4 w;
    w.x = (unsigned)f2bf(fast_tanh(a0 * id)) | ((unsigned)f2bf(fast_tanh(a1 * id)) << 16);
    w.y = (unsigned)f2bf(fast_tanh(a2 * id)) | ((unsigned)f2bf(fast_tanh(a3 * id)) << 16);
    w.z = (unsigned)f2bf(fast_tanh(a4 * id)) | ((unsigned)f2bf(fast_tanh(a5 * id)) << 16);
    w.w = (unsigned)f2bf(fast_tanh(a6 * id)) | ((unsigned)f2bf(fast_tanh(a7 * id)) << 16);
    *reinterpret_cast<uint4*>(fout + (size_t)node * 64 + lane8 * 8) = w;
}

// ---- Fused dual-layer kernel with hand-rolled grid barrier ------------------
// All 784 blocks are co-resident (VGPR capped 128 -> 4 blk/CU cap, 1024 >= 784).
// Barrier: device-scope atomic counter (zeroed by k_prep each iteration) with
// release/acquire __threadfence per Guideline 16 (cross-XCD visibility).
__global__ __launch_bounds__(256, 4) void k_layers(const unsigned int* __restrict__ pedge,
                                                   const float* __restrict__ reln,
                                                   const float* __restrict__ expdot,
                                                   const unsigned short* __restrict__ fin0,
                                                   unsigned short* __restrict__ fin1,
                                                   unsigned short* __restrict__ fin2,
                                                   unsigned int* bar) {
    int tid = threadIdx.x;
    int b = blockIdx.x;
    // ---- layer 1: fin0 -> fin1
    layer_pass(b,        tid, pedge, reln, expdot, fin0, fin1);
    layer_pass(b + NBLK, tid, pedge, reln, expdot, fin0, fin1);
    // ---- grid barrier (no thread returns before this point)
    __threadfence();                 // release fin1 writes (all threads)
    __syncthreads();
    if (tid == 0) {
        atomicAdd(bar, 1u);
        while (atomicAdd(bar, 0u) < (unsigned)NBLK) __builtin_amdgcn_s_sleep(2);
    }
    __syncthreads();
    __threadfence();                 // acquire: fresh fin1 across XCDs
    // ---- layer 2: fin1 -> fin2
    layer_pass(b,        tid, pedge, reln, expdot + RSZ, fin1, fin2);
    layer_pass(b + NBLK, tid, pedge, reln, expdot + RSZ, fin1, fin2);
}

// ---- GATE — R4-exact form (batched B loads, VGPR headroom, linear tiles) ----
__global__ __launch_bounds__(256, 3) void k_gate(const unsigned short* __restrict__ fin0,
                                                 const unsigned short* __restrict__ fin1,
                                                 const unsigned short* __restrict__ fin2,
                                                 const unsigned short* __restrict__ B1,
                                                 const unsigned short* __restrict__ B2,
                                                 const unsigned short* __restrict__ B3,
                                                 const float* __restrict__ pninv,
                                                 const float* __restrict__ gate_b,
                                                 float* __restrict__ dout) {
    __shared__ unsigned short lds[4][16 * LSTR];
    int wv = threadIdx.x >> 6, lane = threadIdx.x & 63;
    int tile = blockIdx.x * 4 + wv;
    if (tile > N_NODES / 16 - 1) tile = N_NODES / 16 - 1;  // dup work, identical writes
    int row0 = tile * 16, lane16 = lane & 15, quad = lane >> 4;
    unsigned short* L = lds[wv];
    const unsigned short* fsel[3] = {fin0, fin1, fin2};

    // o in C-layout (rows quad*4+r, col nt*16+lane16) — independent, issue early
    float oreg[12][4];
#pragma unroll
    for (int nt = 0; nt < 12; nt++) {
        const unsigned short* f = fsel[nt >> 2];
#pragma unroll
        for (int r = 0; r < 4; r++)
            oreg[nt][r] = bf2f(f[(size_t)(row0 + quad * 4 + r) * 64 + (nt & 3) * 16 + lane16]);
    }

    // af: direct 16B bf16 A-fragment loads; sumsq via cvt
    bf16x8 af[6];
    float ss = 0.f;
#pragma unroll
    for (int kt = 0; kt < 6; kt++) {
        const unsigned short* f = fsel[kt >> 1];
        bf16x8 a = *reinterpret_cast<const bf16x8*>(f + (size_t)(row0 + lane16) * 64 + (kt & 1) * 32 + quad * 8);
        af[kt] = a;
#pragma unroll
        for (int i = 0; i < 8; i++) {
            float v = bf2f((unsigned short)a[i]);
            ss = fmaf(v, v, ss);
        }
    }
    ss += __shfl_xor(ss, 16); ss += __shfl_xor(ss, 32);   // full row sumsq at lane&15
    float inv = 1.f / fmaxf(sqrtf(ss), 1e-12f);
    float pni[4];
#pragma unroll
    for (int nt = 0; nt < 4; nt++) pni[nt] = pninv[nt * 16 + lane16];
    f32x4 acc4[4];
#pragma unroll
    for (int nt = 0; nt < 4; nt++) acc4[nt] = (f32x4){0.f, 0.f, 0.f, 0.f};
    // B1 phase: batch 8 fragments (2 kt) per load burst
#pragma unroll
    for (int ktp = 0; ktp < 3; ktp++) {
        bf16x8 bb[8];
#pragma unroll
        for (int h = 0; h < 2; h++)
#pragma unroll
            for (int nt = 0; nt < 4; nt++)
                bb[h * 4 + nt] = *reinterpret_cast<const bf16x8*>(B1 + ((size_t)((ktp * 2 + h) * 4 + nt) * 64 + lane) * 8);
#pragma unroll
        for (int h = 0; h < 2; h++)
#pragma unroll
            for (int nt = 0; nt < 4; nt++)
                acc4[nt] = __builtin_amdgcn_mfma_f32_16x16x32_bf16(af[ktp * 2 + h], bb[h * 4 + nt], acc4[nt], 0, 0, 0);
    }
    // softmax without max-sub: logits are cosine sims in [-1,1]
#pragma unroll
    for (int r = 0; r < 4; r++) {
        int rowloc = quad * 4 + r;
        float invr = __shfl(inv, rowloc);
        float e0 = __expf(acc4[0][r] * invr * pni[0]);
        float e1 = __expf(acc4[1][r] * invr * pni[1]);
        float e2 = __expf(acc4[2][r] * invr * pni[2]);
        float e3 = __expf(acc4[3][r] * invr * pni[3]);
        float s = e0 + e1 + e2 + e3;
        s += __shfl_xor(s, 1); s += __shfl_xor(s, 2);
        s += __shfl_xor(s, 4); s += __shfl_xor(s, 8);
        float rs = 1.f / s;
        L[rowloc * LSTR + lane16]      = f2bf(e0 * rs);
        L[rowloc * LSTR + 16 + lane16] = f2bf(e1 * rs);
        L[rowloc * LSTR + 32 + lane16] = f2bf(e2 * rs);
        L[rowloc * LSTR + 48 + lane16] = f2bf(e3 * rs);
    }
    __threadfence_block();   // drain pa writes (wave-private LDS; no s_barrier)

    f32x4 acc[12];
#pragma unroll
    for (int nt = 0; nt < 12; nt++) acc[nt] = (f32x4){0.f, 0.f, 0.f, 0.f};
    // B2 phase: batch all 12 fragments per kt
#pragma unroll
    for (int kt = 0; kt < 2; kt++) {
        bf16x8 a = *reinterpret_cast<const bf16x8*>(L + lane16 * LSTR + kt * 32 + quad * 8);
        bf16x8 bb[12];
#pragma unroll
        for (int nt = 0; nt < 12; nt++)
            bb[nt] = *reinterpret_cast<const bf16x8*>(B2 + ((size_t)(kt * 12 + nt) * 64 + lane) * 8);
#pragma unroll
        for (int nt = 0; nt < 12; nt++)
            acc[nt] = __builtin_amdgcn_mfma_f32_16x16x32_bf16(a, bb[nt], acc[nt], 0, 0, 0);
    }
    __threadfence_block();   // pa reads complete before pf overwrites rows
#pragma unroll
    for (int nt = 0; nt < 12; nt++) {
#pragma unroll
        for (int r = 0; r < 4; r++) {
            int rowloc = quad * 4 + r;
            L[rowloc * LSTR + nt * 16 + lane16] = f2bf(oreg[nt][r] - acc[nt][r]);
        }
    }
    __threadfence_block();   // drain pf writes

#pragma unroll
    for (int nt = 0; nt < 12; nt++) acc[nt] = (f32x4){0.f, 0.f, 0.f, 0.f};
    // B3 phase: batch all 12 fragments per kt
#pragma unroll
    for (int kt = 0; kt < 6; kt++) {
        bf16x8 a = *reinterpret_cast<const bf16x8*>(L + lane16 * LSTR + kt * 32 + quad * 8);
        bf16x8 bb[12];
#pragma unroll
        for (int nt = 0; nt < 12; nt++)
            bb[nt] = *reinterpret_cast<const bf16x8*>(B3 + ((size_t)(kt * 12 + nt) * 64 + lane) * 8);
#pragma unroll
        for (int nt = 0; nt < 12; nt++)
            acc[nt] = __builtin_amdgcn_mfma_f32_16x16x32_bf16(a, bb[nt], acc[nt], 0, 0, 0);
    }

#pragma unroll
    for (int nt = 0; nt < 12; nt++) {
        float bias = gate_b[nt * 16 + lane16];
#pragma unroll
        for (int r = 0; r < 4; r++) {
            int rowloc = quad * 4 + r;
            size_t idx = (size_t)(row0 + rowloc) * FEATD + nt * 16 + lane16;
            float z = acc[nt][r] + bias;
            float g = 1.f / (1.f + __expf(-z));
            float pf = bf2f(L[rowloc * LSTR + nt * 16 + lane16]);
            dout[idx] = pf + g * (oreg[nt][r] - pf);
        }
    }
}

extern "C" void kernel_launch(void* const* d_in, const int* in_sizes, int n_in,
                              void* d_out, int out_size, void* d_ws, size_t ws_size,
                              hipStream_t stream) {
    (void)in_sizes; (void)n_in; (void)out_size; (void)ws_size;
    const float* features = (const float*)d_in[0];
    const float* rel_emb  = (const float*)d_in[1];
    const float* proxy    = (const float*)d_in[2];
    const float* gate_w   = (const float*)d_in[3];
    const float* gate_b   = (const float*)d_in[4];
    const float* attn_k   = (const float*)d_in[5];
    const int*   adj      = (const int*)d_in[6];
    const int*   r_index  = (const int*)d_in[7];
    // d_in[8] (r_val) unused: positive scale cancels under l2norm; r_index[0]==arange(E).

    unsigned short* fin0 = (unsigned short*)d_ws;           // N*64 bf16
    unsigned short* fin1 = fin0 + (size_t)N_NODES * 64;     // N*64 bf16
    unsigned short* fin2 = fin1 + (size_t)N_NODES * 64;     // N*64 bf16
    float* reln    = (float*)(fin2 + (size_t)N_NODES * 64); // 500*64 fp32
    float* expdot  = reln + RSZ * 64;                       // 2*500
    float* pninv   = expdot + 2 * RSZ;                      // 64
    unsigned short* B1 = (unsigned short*)(pninv + 64);     // 12288
    unsigned short* B2 = B1 + 12288;                        // 12288
    unsigned short* B3 = B2 + 12288;                        // 36864
    unsigned int* pedge = (unsigned int*)(B3 + 36864);      // NEDGE u32
    unsigned int* bar   = pedge + NEDGE;                    // 2 u32 barrier state

    const int* src = adj + NEDGE;       // adj[1]
    const int* rel = r_index + NEDGE;   // r_index[1]

    k_prep   <<<dim3(4678), dim3(256), 0, stream>>>(features, rel_emb, attn_k, proxy, gate_w,
                                                    src, rel, fin0, reln, expdot,
                                                    pninv, B1, B2, B3, pedge, bar);
    k_layers <<<dim3(NBLK), dim3(256), 0, stream>>>(pedge, reln, expdot, fin0, fin1, fin2, bar);
    k_gate   <<<dim3(782),  dim3(256), 0, stream>>>(fin0, fin1, fin2, B1, B2, B3, pninv,
                                                    gate_b, (float*)d_out);
}

// Round 10
// 180.617 us; speedup vs baseline: 2.0487x; 2.0487x over previous
//
#include <hip/hip_runtime.h>
#include <hip/hip_bf16.h>
#include <cstdint>
#include <cstddef>

#define N_NODES 50000
#define DEG     24
#define NEDGE   (N_NODES*DEG)
#define RSZ     500
#define NDIM    64
#define FEATD   192

// LDS row stride (shorts) for the 16x200 per-wave transpose buffer in k_gate.
#define LSTR    200

// k_layer grid: 32 nodes/block (8 lanes x 8 dims per node), 1563 logical blocks,
// padded to 1568 = 8*196 for the XCD swizzle.
#define LGRID   1568
#define LCHUNK  196

typedef short bf16x8 __attribute__((ext_vector_type(8)));
typedef float f32x4  __attribute__((ext_vector_type(4)));

__device__ __forceinline__ unsigned short f2bf(float f) {
    unsigned u = __builtin_bit_cast(unsigned, f);
    unsigned r = (u + 0x7fffu + ((u >> 16) & 1u)) >> 16;   // RNE
    return (unsigned short)r;
}
__device__ __forceinline__ float bf2f(unsigned short s) {
    unsigned u = ((unsigned)s) << 16;
    return __builtin_bit_cast(float, u);
}
__device__ __forceinline__ float lo16(unsigned u) {
    return __builtin_bit_cast(float, u << 16);
}
__device__ __forceinline__ float hi16(unsigned u) {
    return __builtin_bit_cast(float, u & 0xFFFF0000u);
}
__device__ __forceinline__ float fast_tanh(float x) {
    float e = __expf(2.f * x);
    return 1.f - 2.f / (e + 1.f);
}

// ---- PREP (fused) — R4-exact ------------------------------------------------
// Block ranges: [0,3125) tanh, [3125,3250) rel, [3250,3266) pninv,
//               [3266,3506) packB, [3506,4678) packE.
__global__ __launch_bounds__(256) void k_prep(const float* __restrict__ features,
                                              const float* __restrict__ rel_emb,
                                              const float* __restrict__ attn_k,
                                              const float* __restrict__ proxy,
                                              const float* __restrict__ gate_w,
                                              const int* __restrict__ src,
                                              const int* __restrict__ rel,
                                              unsigned short* __restrict__ fin0,
                                              float* __restrict__ reln,
                                              float* __restrict__ expdot,
                                              float* __restrict__ pninv,
                                              unsigned short* __restrict__ B1,
                                              unsigned short* __restrict__ B2,
                                              unsigned short* __restrict__ B3,
                                              unsigned int* __restrict__ pedge) {
    int b = blockIdx.x;
    if (b < 3125) {
        int t = b * 256 + threadIdx.x;             // 800000 threads, 4 elems each
        int idx4 = t * 4;
        float4 f = *reinterpret_cast<const float4*>(features + idx4);
        uint2 w;
        w.x = (unsigned)f2bf(fast_tanh(f.x)) | ((unsigned)f2bf(fast_tanh(f.y)) << 16);
        w.y = (unsigned)f2bf(fast_tanh(f.z)) | ((unsigned)f2bf(fast_tanh(f.w)) << 16);
        *reinterpret_cast<uint2*>(fin0 + idx4) = w;
    } else if (b < 3250) {
        int lane = threadIdx.x & 63;
        int row = (b - 3125) * 4 + (threadIdx.x >> 6);   // 500 rows
        float v = rel_emb[row * 64 + lane];
        float ss = v * v;
        for (int m = 1; m < 64; m <<= 1) ss += __shfl_xor(ss, m);
        float inv = 1.f / fmaxf(sqrtf(ss), 1e-12f);
        float rn = v * inv;
        reln[row * 64 + lane] = rn;
        float d0 = rn * attn_k[lane];
        float d1 = rn * attn_k[64 + lane];
        for (int m = 1; m < 64; m <<= 1) { d0 += __shfl_xor(d0, m); d1 += __shfl_xor(d1, m); }
        if (lane == 0) { expdot[row] = __expf(d0); expdot[RSZ + row] = __expf(d1); }
    } else if (b < 3266) {
        int lane = threadIdx.x & 63;
        int row = (b - 3250) * 4 + (threadIdx.x >> 6);   // 64 rows
        const float* p = proxy + (size_t)row * FEATD;
        float a = p[lane], bb = p[64 + lane], c = p[128 + lane];
        float ss = a * a + bb * bb + c * c;
        for (int m = 1; m < 64; m <<= 1) ss += __shfl_xor(ss, m);
        if (lane == 0) pninv[row] = 1.f / fmaxf(sqrtf(ss), 1e-12f);
    } else if (b < 3506) {
        // B-frag for 16x16x32: lane holds B[k=(lane>>4)*8+j][n=lane&15], j=0..7
        int idx = (b - 3266) * 256 + threadIdx.x;        // 61440 threads
        int j = idx & 7, lane = (idx >> 3) & 63;
        int t = idx >> 9;
        int lane16 = lane & 15, quad = lane >> 4;
        if (t < 24) {                 // B1: Bmat[k][n] = proxy[n][k]
            int kt = t >> 2, nt = t & 3;
            int k = kt * 32 + quad * 8 + j, n = nt * 16 + lane16;
            B1[idx] = f2bf(proxy[(size_t)n * FEATD + k]);
        } else if (t < 48) {          // B2: pa@proxy, Bmat[k][n] = proxy[k][n]
            int tt = t - 24, kt = tt / 12, nt = tt % 12;
            int k = kt * 32 + quad * 8 + j, n = nt * 16 + lane16;
            B2[idx - 12288] = f2bf(proxy[(size_t)k * FEATD + n]);
        } else {                      // B3: pf@gate_w^T, Bmat[k][n] = gate_w[n][k]
            int tt = t - 48, kt = tt / 12, nt = tt % 12;
            int k = kt * 32 + quad * 8 + j, n = nt * 16 + lane16;
            B3[idx - 24576] = f2bf(gate_w[(size_t)n * FEATD + k]);
        }
    } else {
        // pack edges: pe = s | (r<<16)   (s < 65536, r < 512)
        int t = (b - 3506) * 256 + threadIdx.x;          // need 300000
        if (t < NEDGE / 4) {
            int4 s4 = *reinterpret_cast<const int4*>(src + t * 4);
            int4 r4 = *reinterpret_cast<const int4*>(rel + t * 4);
            uint4 o;
            o.x = (unsigned)s4.x | ((unsigned)r4.x << 16);
            o.y = (unsigned)s4.y | ((unsigned)r4.y << 16);
            o.z = (unsigned)s4.z | ((unsigned)r4.z << 16);
            o.w = (unsigned)s4.w | ((unsigned)r4.w << 16);
            *reinterpret_cast<uint4*>(pedge + t * 4) = o;
        }
    }
}

// ---- Layer v6: R0 structure + 1-deep rotating prefetch ----------------------
// R9 evidence: layers are latency-bound on the reln L2 stream (hbm ~1%, VALU
// ~10%). One edge of lookahead (~13 extra VGPRs, no launch_bounds change, no
// wide batch state — R5's 4-wide + VGPR cap was the regression) hides the
// ~200cy reln/fin load latency under the current edge's VALU+shfl work.
__global__ __launch_bounds__(256) void k_layer(const unsigned int* __restrict__ pedge,
                                               const float* __restrict__ reln,
                                               const float* __restrict__ expdot_l,
                                               const unsigned short* __restrict__ fin,
                                               unsigned short* __restrict__ fout) {
    int b = blockIdx.x;
    int lb = (b & 7) * LCHUNK + (b >> 3);
    int lane8 = threadIdx.x & 7;
    int node = lb * 32 + (threadIdx.x >> 3);
    if (node >= N_NODES) return;
    int ebase = node * DEG;
    unsigned pk[DEG];
#pragma unroll
    for (int k = 0; k < DEG; k++) pk[k] = pedge[ebase + k];
    float a0 = 0.f, a1 = 0.f, a2 = 0.f, a3 = 0.f;
    float a4 = 0.f, a5 = 0.f, a6 = 0.f, a7 = 0.f, den = 0.f;
    // prologue: edge 0 operands
    float ex; float4 t0, t1v; uint4 u;
    {
        unsigned p = pk[0];
        int s = p & 0xFFFF, r = p >> 16;
        ex  = expdot_l[r];
        const float* tp = reln + (size_t)r * 64 + lane8 * 8;
        t0  = *reinterpret_cast<const float4*>(tp);
        t1v = *reinterpret_cast<const float4*>(tp + 4);
        u   = *reinterpret_cast<const uint4*>(fin + (size_t)s * 64 + lane8 * 8);
    }
#pragma unroll 4
    for (int k = 0; k < DEG; k++) {
        // rotate current operands out, issue next edge's loads first
        float exc = ex; float4 c0 = t0, c1 = t1v; uint4 cu = u;
        if (k + 1 < DEG) {
            unsigned p = pk[k + 1];
            int s = p & 0xFFFF, r = p >> 16;
            ex  = expdot_l[r];
            const float* tp = reln + (size_t)r * 64 + lane8 * 8;
            t0  = *reinterpret_cast<const float4*>(tp);
            t1v = *reinterpret_cast<const float4*>(tp + 4);
            u   = *reinterpret_cast<const uint4*>(fin + (size_t)s * 64 + lane8 * 8);
        }
        float n0 = lo16(cu.x), n1 = hi16(cu.x), n2 = lo16(cu.y), n3 = hi16(cu.y);
        float n4 = lo16(cu.z), n5 = hi16(cu.z), n6 = lo16(cu.w), n7 = hi16(cu.w);
        float pd = c0.x * n0 + c0.y * n1 + c0.z * n2 + c0.w * n3
                 + c1.x * n4 + c1.y * n5 + c1.z * n6 + c1.w * n7;
        pd += __shfl_xor(pd, 1); pd += __shfl_xor(pd, 2); pd += __shfl_xor(pd, 4);
        float t1 = -2.f * pd * exc;          // acc += ex*(nv - 2*dot*tv)
        a0 = fmaf(exc, n0, fmaf(t1, c0.x, a0));
        a1 = fmaf(exc, n1, fmaf(t1, c0.y, a1));
        a2 = fmaf(exc, n2, fmaf(t1, c0.z, a2));
        a3 = fmaf(exc, n3, fmaf(t1, c0.w, a3));
        a4 = fmaf(exc, n4, fmaf(t1, c1.x, a4));
        a5 = fmaf(exc, n5, fmaf(t1, c1.y, a5));
        a6 = fmaf(exc, n6, fmaf(t1, c1.z, a6));
        a7 = fmaf(exc, n7, fmaf(t1, c1.w, a7));
        den += exc;
    }
    float id = 1.f / den;
    uint4 w;
    w.x = (unsigned)f2bf(fast_tanh(a0 * id)) | ((unsigned)f2bf(fast_tanh(a1 * id)) << 16);
    w.y = (unsigned)f2bf(fast_tanh(a2 * id)) | ((unsigned)f2bf(fast_tanh(a3 * id)) << 16);
    w.z = (unsigned)f2bf(fast_tanh(a4 * id)) | ((unsigned)f2bf(fast_tanh(a5 * id)) << 16);
    w.w = (unsigned)f2bf(fast_tanh(a6 * id)) | ((unsigned)f2bf(fast_tanh(a7 * id)) << 16);
    *reinterpret_cast<uint4*>(fout + (size_t)node * 64 + lane8 * 8) = w;
}

// ---- GATE — R4-exact (batched B loads, VGPR headroom, linear tiles) ---------
__global__ __launch_bounds__(256, 3) void k_gate(const unsigned short* __restrict__ fin0,
                                                 const unsigned short* __restrict__ fin1,
                                                 const unsigned short* __restrict__ fin2,
                                                 const unsigned short* __restrict__ B1,
                                                 const unsigned short* __restrict__ B2,
                                                 const unsigned short* __restrict__ B3,
                                                 const float* __restrict__ pninv,
                                                 const float* __restrict__ gate_b,
                                                 float* __restrict__ dout) {
    __shared__ unsigned short lds[4][16 * LSTR];
    int wv = threadIdx.x >> 6, lane = threadIdx.x & 63;
    int tile = blockIdx.x * 4 + wv;
    if (tile > N_NODES / 16 - 1) tile = N_NODES / 16 - 1;  // dup work, identical writes
    int row0 = tile * 16, lane16 = lane & 15, quad = lane >> 4;
    unsigned short* L = lds[wv];
    const unsigned short* fsel[3] = {fin0, fin1, fin2};

    // o in C-layout (rows quad*4+r, col nt*16+lane16) — independent, issue early
    float oreg[12][4];
#pragma unroll
    for (int nt = 0; nt < 12; nt++) {
        const unsigned short* f = fsel[nt >> 2];
#pragma unroll
        for (int r = 0; r < 4; r++)
            oreg[nt][r] = bf2f(f[(size_t)(row0 + quad * 4 + r) * 64 + (nt & 3) * 16 + lane16]);
    }

    // af: direct 16B bf16 A-fragment loads; sumsq via cvt
    bf16x8 af[6];
    float ss = 0.f;
#pragma unroll
    for (int kt = 0; kt < 6; kt++) {
        const unsigned short* f = fsel[kt >> 1];
        bf16x8 a = *reinterpret_cast<const bf16x8*>(f + (size_t)(row0 + lane16) * 64 + (kt & 1) * 32 + quad * 8);
        af[kt] = a;
#pragma unroll
        for (int i = 0; i < 8; i++) {
            float v = bf2f((unsigned short)a[i]);
            ss = fmaf(v, v, ss);
        }
    }
    ss += __shfl_xor(ss, 16); ss += __shfl_xor(ss, 32);   // full row sumsq at lane&15
    float inv = 1.f / fmaxf(sqrtf(ss), 1e-12f);
    float pni[4];
#pragma unroll
    for (int nt = 0; nt < 4; nt++) pni[nt] = pninv[nt * 16 + lane16];
    f32x4 acc4[4];
#pragma unroll
    for (int nt = 0; nt < 4; nt++) acc4[nt] = (f32x4){0.f, 0.f, 0.f, 0.f};
    // B1 phase: batch 8 fragments (2 kt) per load burst
#pragma unroll
    for (int ktp = 0; ktp < 3; ktp++) {
        bf16x8 bb[8];
#pragma unroll
        for (int h = 0; h < 2; h++)
#pragma unroll
            for (int nt = 0; nt < 4; nt++)
                bb[h * 4 + nt] = *reinterpret_cast<const bf16x8*>(B1 + ((size_t)((ktp * 2 + h) * 4 + nt) * 64 + lane) * 8);
#pragma unroll
        for (int h = 0; h < 2; h++)
#pragma unroll
            for (int nt = 0; nt < 4; nt++)
                acc4[nt] = __builtin_amdgcn_mfma_f32_16x16x32_bf16(af[ktp * 2 + h], bb[h * 4 + nt], acc4[nt], 0, 0, 0);
    }
    // softmax without max-sub: logits are cosine sims in [-1,1]
#pragma unroll
    for (int r = 0; r < 4; r++) {
        int rowloc = quad * 4 + r;
        float invr = __shfl(inv, rowloc);
        float e0 = __expf(acc4[0][r] * invr * pni[0]);
        float e1 = __expf(acc4[1][r] * invr * pni[1]);
        float e2 = __expf(acc4[2][r] * invr * pni[2]);
        float e3 = __expf(acc4[3][r] * invr * pni[3]);
        float s = e0 + e1 + e2 + e3;
        s += __shfl_xor(s, 1); s += __shfl_xor(s, 2);
        s += __shfl_xor(s, 4); s += __shfl_xor(s, 8);
        float rs = 1.f / s;
        L[rowloc * LSTR + lane16]      = f2bf(e0 * rs);
        L[rowloc * LSTR + 16 + lane16] = f2bf(e1 * rs);
        L[rowloc * LSTR + 32 + lane16] = f2bf(e2 * rs);
        L[rowloc * LSTR + 48 + lane16] = f2bf(e3 * rs);
    }
    __threadfence_block();   // drain pa writes (wave-private LDS; no s_barrier)

    f32x4 acc[12];
#pragma unroll
    for (int nt = 0; nt < 12; nt++) acc[nt] = (f32x4){0.f, 0.f, 0.f, 0.f};
    // B2 phase: batch all 12 fragments per kt
#pragma unroll
    for (int kt = 0; kt < 2; kt++) {
        bf16x8 a = *reinterpret_cast<const bf16x8*>(L + lane16 * LSTR + kt * 32 + quad * 8);
        bf16x8 bb[12];
#pragma unroll
        for (int nt = 0; nt < 12; nt++)
            bb[nt] = *reinterpret_cast<const bf16x8*>(B2 + ((size_t)(kt * 12 + nt) * 64 + lane) * 8);
#pragma unroll
        for (int nt = 0; nt < 12; nt++)
            acc[nt] = __builtin_amdgcn_mfma_f32_16x16x32_bf16(a, bb[nt], acc[nt], 0, 0, 0);
    }
    __threadfence_block();   // pa reads complete before pf overwrites rows
#pragma unroll
    for (int nt = 0; nt < 12; nt++) {
#pragma unroll
        for (int r = 0; r < 4; r++) {
            int rowloc = quad * 4 + r;
            L[rowloc * LSTR + nt * 16 + lane16] = f2bf(oreg[nt][r] - acc[nt][r]);
        }
    }
    __threadfence_block();   // drain pf writes

#pragma unroll
    for (int nt = 0; nt < 12; nt++) acc[nt] = (f32x4){0.f, 0.f, 0.f, 0.f};
    // B3 phase: batch all 12 fragments per kt
#pragma unroll
    for (int kt = 0; kt < 6; kt++) {
        bf16x8 a = *reinterpret_cast<const bf16x8*>(L + lane16 * LSTR + kt * 32 + quad * 8);
        bf16x8 bb[12];
#pragma unroll
        for (int nt = 0; nt < 12; nt++)
            bb[nt] = *reinterpret_cast<const bf16x8*>(B3 + ((size_t)(kt * 12 + nt) * 64 + lane) * 8);
#pragma unroll
        for (int nt = 0; nt < 12; nt++)
            acc[nt] = __builtin_amdgcn_mfma_f32_16x16x32_bf16(a, bb[nt], acc[nt], 0, 0, 0);
    }

#pragma unroll
    for (int nt = 0; nt < 12; nt++) {
        float bias = gate_b[nt * 16 + lane16];
#pragma unroll
        for (int r = 0; r < 4; r++) {
            int rowloc = quad * 4 + r;
            size_t idx = (size_t)(row0 + rowloc) * FEATD + nt * 16 + lane16;
            float z = acc[nt][r] + bias;
            float g = 1.f / (1.f + __expf(-z));
            float pf = bf2f(L[rowloc * LSTR + nt * 16 + lane16]);
            dout[idx] = pf + g * (oreg[nt][r] - pf);
        }
    }
}

extern "C" void kernel_launch(void* const* d_in, const int* in_sizes, int n_in,
                              void* d_out, int out_size, void* d_ws, size_t ws_size,
                              hipStream_t stream) {
    (void)in_sizes; (void)n_in; (void)out_size; (void)ws_size;
    const float* features = (const float*)d_in[0];
    const float* rel_emb  = (const float*)d_in[1];
    const float* proxy    = (const float*)d_in[2];
    const float* gate_w   = (const float*)d_in[3];
    const float* gate_b   = (const float*)d_in[4];
    const float* attn_k   = (const float*)d_in[5];
    const int*   adj      = (const int*)d_in[6];
    const int*   r_index  = (const int*)d_in[7];
    // d_in[8] (r_val) unused: positive scale cancels under l2norm; r_index[0]==arange(E).

    unsigned short* fin0 = (unsigned short*)d_ws;           // N*64 bf16
    unsigned short* fin1 = fin0 + (size_t)N_NODES * 64;     // N*64 bf16
    unsigned short* fin2 = fin1 + (size_t)N_NODES * 64;     // N*64 bf16
    float* reln    = (float*)(fin2 + (size_t)N_NODES * 64); // 500*64 fp32
    float* expdot  = reln + RSZ * 64;                       // 2*500
    float* pninv   = expdot + 2 * RSZ;                      // 64
    unsigned short* B1 = (unsigned short*)(pninv + 64);     // 12288
    unsigned short* B2 = B1 + 12288;                        // 12288
    unsigned short* B3 = B2 + 12288;                        // 36864
    unsigned int* pedge = (unsigned int*)(B3 + 36864);      // NEDGE u32

    const int* src = adj + NEDGE;       // adj[1]
    const int* rel = r_index + NEDGE;   // r_index[1]

    k_prep  <<<dim3(4678), dim3(256), 0, stream>>>(features, rel_emb, attn_k, proxy, gate_w,
                                                   src, rel, fin0, reln, expdot,
                                                   pninv, B1, B2, B3, pedge);
    k_layer <<<dim3(LGRID), dim3(256), 0, stream>>>(pedge, reln, expdot,       fin0, fin1);
    k_layer <<<dim3(LGRID), dim3(256), 0, stream>>>(pedge, reln, expdot + RSZ, fin1, fin2);
    k_gate  <<<dim3(782),  dim3(256), 0, stream>>>(fin0, fin1, fin2, B1, B2, B3, pninv,
                                                   gate_b, (float*)d_out);
}